// Round 5
// baseline (7291.877 us; speedup 1.0000x reference)
//
#include <hip/hip_runtime.h>
#include <hip/hip_bf16.h>
#include <cstdint>
#include <cstddef>

// MMDecoderDoubleBranch R5: 64 rows per wave (4 M-tiles), single-wave blocks.
// Governing law (R2 vs R4 measured): weight traffic = #waves x 557KB x 30 steps.
// 64 rows/wave halves R2's traffic (8.4 GB L2) and gives 1:4 load:MFMA reuse.
// 512 blocks x 64 thr, 2 blocks/CU, __launch_bounds__(64,1) -> 512-VGPR budget.
// cacc + accumulators in regs; residual h re-read from LDS f16 (err ~5e-4).

#define HD 128
#define TT 30
#define MM 6
#define B_ROWS 32768

typedef _Float16 f16x8 __attribute__((ext_vector_type(8)));
typedef float f32x4 __attribute__((ext_vector_type(4)));

__device__ __forceinline__ float fast_rcp(float x) { return __builtin_amdgcn_rcpf(x); }
__device__ __forceinline__ float sigm(float x) { return fast_rcp(1.f + __expf(-x)); }
__device__ __forceinline__ float tanhf_(float x) { return 1.f - 2.f * fast_rcp(__expf(2.f * x) + 1.f); }
__device__ __forceinline__ float selu_(float x) {
  const float sc = 1.0507009873554805f;
  const float al = 1.6732632423543772f;
  return x > 0.f ? sc * x : sc * al * (__expf(x) - 1.f);
}

__device__ __forceinline__ f32x4 shx4(f32x4 v, int m) {
  f32x4 r;
  r[0] = __shfl_xor(v[0], m, 64);
  r[1] = __shfl_xor(v[1], m, 64);
  r[2] = __shfl_xor(v[2], m, 64);
  r[3] = __shfl_xor(v[3], m, 64);
  return r;
}

// ---- weight prep: fragment-ordered f16 (layouts unchanged since R2) ----
__global__ __launch_bounds__(256) void prep_weights(
    const float* __restrict__ W_ih, const float* __restrict__ W_hh,
    const float* __restrict__ b_ih, const float* __restrict__ b_hh,
    const float* __restrict__ mW1, const float* __restrict__ mW2,
    const float* __restrict__ cW1, const float* __restrict__ cW2,
    _Float16* __restrict__ Wg, _Float16* __restrict__ W1p, _Float16* __restrict__ W2p,
    _Float16* __restrict__ cW1p, _Float16* __restrict__ cW2p, float* __restrict__ bg) {
  int n = blockIdx.x * 256 + threadIdx.x;
  if (n < 81920) {
    int t16 = n / 2560, r = n % 2560;
    int ch = r / 512, l = (r >> 3) & 63, j = r & 7;
    int q = l >> 4, cl = l & 15;
    int row = (t16 >> 3) * 128 + (t16 & 7) * 16 + cl;
    int k = ch * 32 + q * 8 + j;
    float v = 0.f;
    if (k < 128) v = W_hh[row * 128 + k];
    else if (k < 144) v = W_ih[row * 16 + (k - 128)];
    Wg[n] = (_Float16)v;
    return;
  }
  n -= 81920;
  if (n < 98304) {
    int m = n >> 14, r = n & 16383;
    int ct = r >> 11, ch = (r >> 9) & 3, l = (r >> 3) & 63, j = r & 7;
    int q = l >> 4, cl = l & 15;
    int outcol = ct * 16 + cl, k = ch * 32 + q * 8 + j;
    W1p[n] = (_Float16)mW1[(m * 128 + k) * 128 + outcol];
    return;
  }
  n -= 98304;
  if (n < 98304) {
    int m = n >> 14, r = n & 16383;
    int ct = r >> 11, ch = (r >> 9) & 3, l = (r >> 3) & 63, j = r & 7;
    int q = l >> 4, cl = l & 15;
    int outcol = ct * 16 + cl, k = ch * 32 + q * 8 + j;
    W2p[n] = (_Float16)mW2[(m * 128 + k) * 128 + outcol];
    return;
  }
  n -= 98304;
  if (n < 16384) {
    int ct = n >> 11, ch = (n >> 9) & 3, l = (n >> 3) & 63, j = n & 7;
    int q = l >> 4, cl = l & 15;
    int outcol = ct * 16 + cl, k = ch * 32 + q * 8 + j;
    cW1p[n] = (_Float16)cW1[k * 128 + outcol];
    return;
  }
  n -= 16384;
  if (n < 16384) {
    int ct = n >> 11, ch = (n >> 9) & 3, l = (n >> 3) & 63, j = n & 7;
    int q = l >> 4, cl = l & 15;
    int outcol = ct * 16 + cl, k = ch * 32 + q * 8 + j;
    cW2p[n] = (_Float16)cW2[k * 128 + outcol];
    return;
  }
  n -= 16384;
  if (n < 512) bg[n] = b_ih[n] + b_hh[n];
}

// ---- main decoder: 1 wave per block, 64 rows (4 M-tiles) per wave ----
__global__ __launch_bounds__(64, 1) void mmdec_main(
    const float* __restrict__ last_obs_rel, const float* __restrict__ h0, const float* __restrict__ c0,
    const float* __restrict__ W_se, const float* __restrict__ b_se,
    const float* __restrict__ mg1w, const float* __restrict__ mg1b,
    const float* __restrict__ mg2w, const float* __restrict__ mg2b,
    const float* __restrict__ mWo, const float* __restrict__ mbo,
    const float* __restrict__ cg1w, const float* __restrict__ cg1b,
    const float* __restrict__ cg2w, const float* __restrict__ cg2b,
    const float* __restrict__ cWo, const float* __restrict__ cbo,
    const _Float16* __restrict__ Wg, const _Float16* __restrict__ W1p, const _Float16* __restrict__ W2p,
    const _Float16* __restrict__ cW1p, const _Float16* __restrict__ cW2p, const float* __restrict__ bgp,
    float* __restrict__ out) {
  // h rows: [128 h | 16 x | 16 zeros] f16, stride 336 B (16B-aligned, non-pow2)
  __shared__ __align__(16) unsigned char h_smem[64 * 336];
  __shared__ __align__(16) unsigned char t1_smem[64 * 272];
  __shared__ float rel_smem[64 * 12];

  const int lane = threadIdx.x;
  const int q = lane >> 4, cl = lane & 15;
  const int rowbase = blockIdx.x * 64;

  auto hrow = [&](int r) -> _Float16* { return (_Float16*)(h_smem + r * 336); };
  auto t1row = [&](int r) -> _Float16* { return (_Float16*)(t1_smem + r * 272); };

  // ---- init: h0 -> LDS f16 (one row per lane) ----
  {
    const float* src = h0 + (size_t)(rowbase + lane) * HD;
    _Float16* dst = hrow(lane);
#pragma unroll
    for (int i = 0; i < 128; i += 8) {
      f16x8 v;
#pragma unroll
      for (int k = 0; k < 8; ++k) v[k] = (_Float16)src[i + k];
      *(f16x8*)(dst + i) = v;
    }
    // x = selu(tile(last_obs_rel,6) @ W_se.T + b_se); zero pad
    const float r0 = last_obs_rel[(size_t)(rowbase + lane) * 2 + 0];
    const float r1 = last_obs_rel[(size_t)(rowbase + lane) * 2 + 1];
#pragma unroll
    for (int e = 0; e < 16; ++e) {
      float acc = b_se[e];
#pragma unroll
      for (int j = 0; j < 12; ++j) acc += ((j & 1) ? r1 : r0) * W_se[e * 12 + j];
      dst[128 + e] = (_Float16)selu_(acc);
    }
    f16x8 z;
#pragma unroll
    for (int i = 0; i < 8; ++i) z[i] = (_Float16)0.f;
    *(f16x8*)(dst + 144) = z;
    *(f16x8*)(dst + 152) = z;
  }
  // ---- init: c0 in C-layout regs: [rt][cg], row = rt*16+q*4+r, col = cg*16+cl ----
  f32x4 cacc[4][8];
#pragma unroll
  for (int rt = 0; rt < 4; ++rt)
#pragma unroll
    for (int cg = 0; cg < 8; ++cg)
#pragma unroll
      for (int r = 0; r < 4; ++r)
        cacc[rt][cg][r] = c0[(size_t)(rowbase + rt * 16 + q * 4 + r) * HD + cg * 16 + cl];
  float bgh[8][4];
#pragma unroll
  for (int cg = 0; cg < 8; ++cg)
#pragma unroll
    for (int g = 0; g < 4; ++g) bgh[cg][g] = bgp[g * 128 + cg * 16 + cl];
  __syncthreads();

  const size_t confbase = (size_t)B_ROWS * MM * TT * 2;

  for (int t = 0; t < TT; ++t) {
    // ======== LSTM: [h|x|0](K=160) @ Wg^T; update c, write h(t) ========
    f16x8 afr[4][5];
#pragma unroll
    for (int rt = 0; rt < 4; ++rt)
#pragma unroll
      for (int ch = 0; ch < 5; ++ch)
        afr[rt][ch] = *(const f16x8*)(hrow(rt * 16 + cl) + ch * 32 + q * 8);
    __syncthreads();  // reads of h(t-1)/x done before h(t) scatter below

#pragma unroll
    for (int cg = 0; cg < 8; ++cg) {
      f32x4 gacc[4][4];  // [g][rt]
#pragma unroll
      for (int g = 0; g < 4; ++g)
#pragma unroll
        for (int rt = 0; rt < 4; ++rt) gacc[g][rt] = f32x4{0.f, 0.f, 0.f, 0.f};
#pragma unroll
      for (int g = 0; g < 4; ++g) {
        const _Float16* bp = Wg + (size_t)(g * 8 + cg) * 2560 + lane * 8;
#pragma unroll
        for (int ch = 0; ch < 5; ++ch) {
          f16x8 b = *(const f16x8*)(bp + ch * 512);
#pragma unroll
          for (int rt = 0; rt < 4; ++rt)
            gacc[g][rt] = __builtin_amdgcn_mfma_f32_16x16x32_f16(afr[rt][ch], b, gacc[g][rt], 0, 0, 0);
        }
      }
#pragma unroll
      for (int rt = 0; rt < 4; ++rt) {
#pragma unroll
        for (int r = 0; r < 4; ++r) {
          const float iv = sigm(gacc[0][rt][r] + bgh[cg][0]);
          const float fv = sigm(gacc[1][rt][r] + bgh[cg][1]);
          const float gv = tanhf_(gacc[2][rt][r] + bgh[cg][2]);
          const float ov = sigm(gacc[3][rt][r] + bgh[cg][3]);
          const float cn = fv * cacc[rt][cg][r] + iv * gv;
          cacc[rt][cg][r] = cn;
          hrow(rt * 16 + q * 4 + r)[cg * 16 + cl] = (_Float16)(ov * tanhf_(cn));
        }
      }
    }
    __syncthreads();  // h(t) visible

    // ======== 6 mode heads ========
    for (int m = 0; m < MM; ++m) {
      // gemm1: t = h @ mW1[m]   (A-frags reloaded per mode; frag regs shared w/ gemm2)
      f16x8 frag[4][4];
#pragma unroll
      for (int rt = 0; rt < 4; ++rt)
#pragma unroll
        for (int ch = 0; ch < 4; ++ch)
          frag[rt][ch] = *(const f16x8*)(hrow(rt * 16 + cl) + ch * 32 + q * 8);
      f32x4 acc1[8][4];  // [ct][rt]
#pragma unroll
      for (int ct = 0; ct < 8; ++ct) {
        const _Float16* bp = W1p + (size_t)m * 16384 + ct * 2048 + lane * 8;
#pragma unroll
        for (int rt = 0; rt < 4; ++rt) acc1[ct][rt] = f32x4{0.f, 0.f, 0.f, 0.f};
#pragma unroll
        for (int ch = 0; ch < 4; ++ch) {
          f16x8 b = *(const f16x8*)(bp + ch * 512);
#pragma unroll
          for (int rt = 0; rt < 4; ++rt)
            acc1[ct][rt] = __builtin_amdgcn_mfma_f32_16x16x32_f16(frag[rt][ch], b, acc1[ct][rt], 0, 0, 0);
        }
      }
      // GN1 stats (in-wave butterfly over cl)
      f32x4 mean[4], rstd[4];
#pragma unroll
      for (int rt = 0; rt < 4; ++rt) {
        f32x4 s1 = {0.f, 0.f, 0.f, 0.f}, s2 = {0.f, 0.f, 0.f, 0.f};
#pragma unroll
        for (int ct = 0; ct < 8; ++ct) { s1 += acc1[ct][rt]; s2 += acc1[ct][rt] * acc1[ct][rt]; }
#pragma unroll
        for (int sh = 1; sh < 16; sh <<= 1) { s1 += shx4(s1, sh); s2 += shx4(s2, sh); }
        mean[rt] = s1 * (1.f / 128.f);
#pragma unroll
        for (int r = 0; r < 4; ++r)
          rstd[rt][r] = rsqrtf(s2[r] * (1.f / 128.f) - mean[rt][r] * mean[rt][r] + 1e-5f);
      }
      __syncthreads();  // WAR: prev mode's t1 A-frag reads done before overwrite
      // t1 = relu(gn1) -> LDS (C-layout scatter)
#pragma unroll
      for (int ct = 0; ct < 8; ++ct) {
        const float g1 = mg1w[m * HD + ct * 16 + cl];
        const float b1 = mg1b[m * HD + ct * 16 + cl];
#pragma unroll
        for (int rt = 0; rt < 4; ++rt)
#pragma unroll
          for (int r = 0; r < 4; ++r) {
            float v = (acc1[ct][rt][r] - mean[rt][r]) * rstd[rt][r] * g1 + b1;
            t1row(rt * 16 + q * 4 + r)[ct * 16 + cl] = (_Float16)fmaxf(v, 0.f);
          }
      }
      __syncthreads();  // t1 visible
      // gemm2: t2 = t1 @ mW2[m]
#pragma unroll
      for (int rt = 0; rt < 4; ++rt)
#pragma unroll
        for (int ch = 0; ch < 4; ++ch)
          frag[rt][ch] = *(const f16x8*)(t1row(rt * 16 + cl) + ch * 32 + q * 8);
      f32x4 acc2[8][4];
#pragma unroll
      for (int ct = 0; ct < 8; ++ct) {
        const _Float16* bp = W2p + (size_t)m * 16384 + ct * 2048 + lane * 8;
#pragma unroll
        for (int rt = 0; rt < 4; ++rt) acc2[ct][rt] = f32x4{0.f, 0.f, 0.f, 0.f};
#pragma unroll
        for (int ch = 0; ch < 4; ++ch) {
          f16x8 b = *(const f16x8*)(bp + ch * 512);
#pragma unroll
          for (int rt = 0; rt < 4; ++rt)
            acc2[ct][rt] = __builtin_amdgcn_mfma_f32_16x16x32_f16(frag[rt][ch], b, acc2[ct][rt], 0, 0, 0);
        }
      }
      // GN2 stats
#pragma unroll
      for (int rt = 0; rt < 4; ++rt) {
        f32x4 s1 = {0.f, 0.f, 0.f, 0.f}, s2 = {0.f, 0.f, 0.f, 0.f};
#pragma unroll
        for (int ct = 0; ct < 8; ++ct) { s1 += acc2[ct][rt]; s2 += acc2[ct][rt] * acc2[ct][rt]; }
#pragma unroll
        for (int sh = 1; sh < 16; sh <<= 1) { s1 += shx4(s1, sh); s2 += shx4(s2, sh); }
        mean[rt] = s1 * (1.f / 128.f);
#pragma unroll
        for (int r = 0; r < 4; ++r)
          rstd[rt][r] = rsqrtf(s2[r] * (1.f / 128.f) - mean[rt][r] * mean[rt][r] + 1e-5f);
      }
      // t = relu(gn2 + h)  [h residual re-read from LDS f16]; out-proj
      f32x4 po0[4], po1[4];
#pragma unroll
      for (int rt = 0; rt < 4; ++rt) { po0[rt] = f32x4{0.f, 0.f, 0.f, 0.f}; po1[rt] = f32x4{0.f, 0.f, 0.f, 0.f}; }
#pragma unroll
      for (int ct = 0; ct < 8; ++ct) {
        const float g2 = mg2w[m * HD + ct * 16 + cl];
        const float b2 = mg2b[m * HD + ct * 16 + cl];
        const float w0 = mWo[((size_t)m * HD + ct * 16 + cl) * 2 + 0];
        const float w1 = mWo[((size_t)m * HD + ct * 16 + cl) * 2 + 1];
#pragma unroll
        for (int rt = 0; rt < 4; ++rt)
#pragma unroll
          for (int r = 0; r < 4; ++r) {
            const float hres = (float)hrow(rt * 16 + q * 4 + r)[ct * 16 + cl];
            float v = (acc2[ct][rt][r] - mean[rt][r]) * rstd[rt][r] * g2 + b2 + hres;
            v = fmaxf(v, 0.f);
            po0[rt][r] += v * w0;
            po1[rt][r] += v * w1;
          }
      }
#pragma unroll
      for (int sh = 1; sh < 16; sh <<= 1)
#pragma unroll
        for (int rt = 0; rt < 4; ++rt) { po0[rt] += shx4(po0[rt], sh); po1[rt] += shx4(po1[rt], sh); }
      if (cl < 2) {
#pragma unroll
        for (int rt = 0; rt < 4; ++rt)
#pragma unroll
          for (int r = 0; r < 4; ++r) {
            const int rl_ = rt * 16 + q * 4 + r;
            const float val = (cl ? po1[rt][r] : po0[rt][r]) + mbo[m * 2 + cl];
            out[(((size_t)(rowbase + rl_) * MM + m) * TT + t) * 2 + cl] = val;
            rel_smem[rl_ * 12 + m * 2 + cl] = val;
          }
      }
    }
    __syncthreads();  // rel complete

    // ======== xin = selu(rel @ W_se.T + b_se) -> x cols (one row per lane) ========
    {
      float rl[12];
#pragma unroll
      for (int j = 0; j < 12; ++j) rl[j] = rel_smem[lane * 12 + j];
      _Float16* dst = hrow(lane);
#pragma unroll
      for (int e = 0; e < 16; ++e) {
        float acc = b_se[e];
#pragma unroll
        for (int j = 0; j < 12; ++j) acc += rl[j] * W_se[e * 12 + j];
        dst[128 + e] = (_Float16)selu_(acc);
      }
    }
    __syncthreads();  // x ready for next step
  }

  // ======== confidence head on hT ========
  {
    f16x8 frag[4][4];
#pragma unroll
    for (int rt = 0; rt < 4; ++rt)
#pragma unroll
      for (int ch = 0; ch < 4; ++ch)
        frag[rt][ch] = *(const f16x8*)(hrow(rt * 16 + cl) + ch * 32 + q * 8);
    f32x4 acc1[8][4];
#pragma unroll
    for (int ct = 0; ct < 8; ++ct) {
      const _Float16* bp = cW1p + ct * 2048 + lane * 8;
#pragma unroll
      for (int rt = 0; rt < 4; ++rt) acc1[ct][rt] = f32x4{0.f, 0.f, 0.f, 0.f};
#pragma unroll
      for (int ch = 0; ch < 4; ++ch) {
        f16x8 b = *(const f16x8*)(bp + ch * 512);
#pragma unroll
        for (int rt = 0; rt < 4; ++rt)
          acc1[ct][rt] = __builtin_amdgcn_mfma_f32_16x16x32_f16(frag[rt][ch], b, acc1[ct][rt], 0, 0, 0);
      }
    }
    f32x4 mean[4], rstd[4];
#pragma unroll
    for (int rt = 0; rt < 4; ++rt) {
      f32x4 s1 = {0.f, 0.f, 0.f, 0.f}, s2 = {0.f, 0.f, 0.f, 0.f};
#pragma unroll
      for (int ct = 0; ct < 8; ++ct) { s1 += acc1[ct][rt]; s2 += acc1[ct][rt] * acc1[ct][rt]; }
#pragma unroll
      for (int sh = 1; sh < 16; sh <<= 1) { s1 += shx4(s1, sh); s2 += shx4(s2, sh); }
      mean[rt] = s1 * (1.f / 128.f);
#pragma unroll
      for (int r = 0; r < 4; ++r)
        rstd[rt][r] = rsqrtf(s2[r] * (1.f / 128.f) - mean[rt][r] * mean[rt][r] + 1e-5f);
    }
    __syncthreads();
#pragma unroll
    for (int ct = 0; ct < 8; ++ct) {
      const float g1 = cg1w[ct * 16 + cl];
      const float b1 = cg1b[ct * 16 + cl];
#pragma unroll
      for (int rt = 0; rt < 4; ++rt)
#pragma unroll
        for (int r = 0; r < 4; ++r) {
          float v = (acc1[ct][rt][r] - mean[rt][r]) * rstd[rt][r] * g1 + b1;
          t1row(rt * 16 + q * 4 + r)[ct * 16 + cl] = (_Float16)fmaxf(v, 0.f);
        }
    }
    __syncthreads();
#pragma unroll
    for (int rt = 0; rt < 4; ++rt)
#pragma unroll
      for (int ch = 0; ch < 4; ++ch)
        frag[rt][ch] = *(const f16x8*)(t1row(rt * 16 + cl) + ch * 32 + q * 8);
    f32x4 acc2[8][4];
#pragma unroll
    for (int ct = 0; ct < 8; ++ct) {
      const _Float16* bp = cW2p + ct * 2048 + lane * 8;
#pragma unroll
      for (int rt = 0; rt < 4; ++rt) acc2[ct][rt] = f32x4{0.f, 0.f, 0.f, 0.f};
#pragma unroll
      for (int ch = 0; ch < 4; ++ch) {
        f16x8 b = *(const f16x8*)(bp + ch * 512);
#pragma unroll
        for (int rt = 0; rt < 4; ++rt)
          acc2[ct][rt] = __builtin_amdgcn_mfma_f32_16x16x32_f16(frag[rt][ch], b, acc2[ct][rt], 0, 0, 0);
      }
    }
#pragma unroll
    for (int rt = 0; rt < 4; ++rt) {
      f32x4 s1 = {0.f, 0.f, 0.f, 0.f}, s2 = {0.f, 0.f, 0.f, 0.f};
#pragma unroll
      for (int ct = 0; ct < 8; ++ct) { s1 += acc2[ct][rt]; s2 += acc2[ct][rt] * acc2[ct][rt]; }
#pragma unroll
      for (int sh = 1; sh < 16; sh <<= 1) { s1 += shx4(s1, sh); s2 += shx4(s2, sh); }
      mean[rt] = s1 * (1.f / 128.f);
#pragma unroll
      for (int r = 0; r < 4; ++r)
        rstd[rt][r] = rsqrtf(s2[r] * (1.f / 128.f) - mean[rt][r] * mean[rt][r] + 1e-5f);
    }
    float pl[4][4][6];
#pragma unroll
    for (int rt = 0; rt < 4; ++rt)
#pragma unroll
      for (int r = 0; r < 4; ++r)
#pragma unroll
        for (int k = 0; k < 6; ++k) pl[rt][r][k] = 0.f;
#pragma unroll
    for (int ct = 0; ct < 8; ++ct) {
      const float g2 = cg2w[ct * 16 + cl];
      const float b2 = cg2b[ct * 16 + cl];
      float wo[6];
#pragma unroll
      for (int k = 0; k < 6; ++k) wo[k] = cWo[(ct * 16 + cl) * 6 + k];
#pragma unroll
      for (int rt = 0; rt < 4; ++rt)
#pragma unroll
        for (int r = 0; r < 4; ++r) {
          const float hres = (float)hrow(rt * 16 + q * 4 + r)[ct * 16 + cl];
          float v = (acc2[ct][rt][r] - mean[rt][r]) * rstd[rt][r] * g2 + b2 + hres;
          v = fmaxf(v, 0.f);
#pragma unroll
          for (int k = 0; k < 6; ++k) pl[rt][r][k] += v * wo[k];
        }
    }
#pragma unroll
    for (int sh = 1; sh < 16; sh <<= 1)
#pragma unroll
      for (int rt = 0; rt < 4; ++rt)
#pragma unroll
        for (int r = 0; r < 4; ++r)
#pragma unroll
          for (int k = 0; k < 6; ++k) pl[rt][r][k] += __shfl_xor(pl[rt][r][k], sh, 64);
    if (cl == 0) {
#pragma unroll
      for (int rt = 0; rt < 4; ++rt)
#pragma unroll
        for (int r = 0; r < 4; ++r) {
          float l[6];
#pragma unroll
          for (int k = 0; k < 6; ++k) l[k] = pl[rt][r][k] + cbo[k];
          float mx = l[0];
#pragma unroll
          for (int k = 1; k < 6; ++k) mx = fmaxf(mx, l[k]);
          float s = 0.f;
#pragma unroll
          for (int k = 0; k < 6; ++k) { l[k] = __expf(l[k] - mx); s += l[k]; }
          const float inv = fast_rcp(s);
#pragma unroll
          for (int k = 0; k < 6; ++k)
            out[confbase + (size_t)(rowbase + rt * 16 + q * 4 + r) * 6 + k] = l[k] * inv;
        }
    }
  }
}

extern "C" void kernel_launch(void* const* d_in, const int* in_sizes, int n_in,
                              void* d_out, int out_size, void* d_ws, size_t ws_size,
                              hipStream_t stream) {
  (void)in_sizes; (void)n_in; (void)out_size; (void)ws_size;
  const float* last_obs_rel = (const float*)d_in[1];
  const float* h0   = (const float*)d_in[2];
  const float* c0   = (const float*)d_in[3];
  const float* W_se = (const float*)d_in[4];
  const float* b_se = (const float*)d_in[5];
  const float* W_ih = (const float*)d_in[6];
  const float* W_hh = (const float*)d_in[7];
  const float* b_ih = (const float*)d_in[8];
  const float* b_hh = (const float*)d_in[9];
  const float* mW1  = (const float*)d_in[10];
  const float* mg1w = (const float*)d_in[11];
  const float* mg1b = (const float*)d_in[12];
  const float* mW2  = (const float*)d_in[13];
  const float* mg2w = (const float*)d_in[14];
  const float* mg2b = (const float*)d_in[15];
  const float* mWo  = (const float*)d_in[16];
  const float* mbo  = (const float*)d_in[17];
  const float* cW1  = (const float*)d_in[18];
  const float* cg1w = (const float*)d_in[19];
  const float* cg1b = (const float*)d_in[20];
  const float* cW2  = (const float*)d_in[21];
  const float* cg2w = (const float*)d_in[22];
  const float* cg2b = (const float*)d_in[23];
  const float* cWo  = (const float*)d_in[24];
  const float* cbo  = (const float*)d_in[25];

  char* ws = (char*)d_ws;
  _Float16* Wg   = (_Float16*)(ws + 0);       // 512*160 f16   = 163840 B
  _Float16* W1p  = (_Float16*)(ws + 163840);  // 6*128*128 f16 = 196608 B
  _Float16* W2p  = (_Float16*)(ws + 360448);  // 6*128*128 f16 = 196608 B
  _Float16* cW1p = (_Float16*)(ws + 557056);  // 128*128 f16   =  32768 B
  _Float16* cW2p = (_Float16*)(ws + 589824);  // 128*128 f16   =  32768 B
  float*    bg   = (float*)   (ws + 622592);  // 512 f32       =   2048 B

  prep_weights<<<1218, 256, 0, stream>>>(W_ih, W_hh, b_ih, b_hh, mW1, mW2, cW1, cW2,
                                         Wg, W1p, W2p, cW1p, cW2p, bg);
  mmdec_main<<<B_ROWS / 64, 64, 0, stream>>>(last_obs_rel, h0, c0, W_se, b_se,
                                             mg1w, mg1b, mg2w, mg2b, mWo, mbo,
                                             cg1w, cg1b, cg2w, cg2b, cWo, cbo,
                                             Wg, W1p, W2p, cW1p, cW2p, bg, (float*)d_out);
}

// Round 6
// 2808.426 us; speedup vs baseline: 2.5964x; 2.5964x over previous
//
#include <hip/hip_runtime.h>
#include <hip/hip_bf16.h>
#include <cstdint>
#include <cstddef>

// MMDecoderDoubleBranch R6: weights staged GLOBAL->LDS per block per step.
// Measured law (R2/R4/R5): HBM traffic = 14.5% x (#waves x 557KB x 30) when
// waves stream weights from global; BW collapses below ~1024 waves. Fix:
// 256 blocks x 4 waves x 32 rows/wave; weights go through LDS once per BLOCK
// per step (demand /4 vs R2) while keeping 1024 waves of parallelism.
// Staging: double-buffered 20KB chunks via global_load_lds (width 16; the
// fragment-ordered layout is exactly base+lane*16B). 32 chunks/step, one
// __syncthreads each. h/t1/rel are wave-private (intra-wave LDS is in-order
// per wave) -> no cross-wave data flow; barriers exist only for staging.
// Wg re-packed cg-major (tile = cg*4+g) so each 20KB chunk = complete
// i/f/g/o gate set for 16 channels.

#define HD 128
#define TT 30
#define MM 6
#define B_ROWS 32768

typedef _Float16 f16x8 __attribute__((ext_vector_type(8)));
typedef float f32x4 __attribute__((ext_vector_type(4)));

__device__ __forceinline__ float fast_rcp(float x) { return __builtin_amdgcn_rcpf(x); }
__device__ __forceinline__ float sigm(float x) { return fast_rcp(1.f + __expf(-x)); }
__device__ __forceinline__ float tanhf_(float x) { return 1.f - 2.f * fast_rcp(__expf(2.f * x) + 1.f); }
__device__ __forceinline__ float selu_(float x) {
  const float sc = 1.0507009873554805f;
  const float al = 1.6732632423543772f;
  return x > 0.f ? sc * x : sc * al * (__expf(x) - 1.f);
}

__device__ __forceinline__ f32x4 shx4(f32x4 v, int m) {
  f32x4 r;
  r[0] = __shfl_xor(v[0], m, 64);
  r[1] = __shfl_xor(v[1], m, 64);
  r[2] = __shfl_xor(v[2], m, 64);
  r[3] = __shfl_xor(v[3], m, 64);
  return r;
}

// ---- weight prep: fragment-ordered f16 ----
// Wg: 32 tiles of 2560 f16, tile index T = cg*4+g (cg-major!), inside:
//     [ch=0..4][lane][8].  Chunk cg = Wg + cg*10240 (4 tiles = 20KB).
// W1p/W2p: per mode [ct][ch=0..3][lane][8]; cW1p/cW2p: [ct][ch][lane][8].
__global__ __launch_bounds__(256) void prep_weights(
    const float* __restrict__ W_ih, const float* __restrict__ W_hh,
    const float* __restrict__ b_ih, const float* __restrict__ b_hh,
    const float* __restrict__ mW1, const float* __restrict__ mW2,
    const float* __restrict__ cW1, const float* __restrict__ cW2,
    _Float16* __restrict__ Wg, _Float16* __restrict__ W1p, _Float16* __restrict__ W2p,
    _Float16* __restrict__ cW1p, _Float16* __restrict__ cW2p, float* __restrict__ bg) {
  int n = blockIdx.x * 256 + threadIdx.x;
  if (n < 81920) {
    int t16 = n / 2560, r = n % 2560;
    int ch = r / 512, l = (r >> 3) & 63, j = r & 7;
    int q = l >> 4, cl = l & 15;
    int cg = t16 >> 2, g = t16 & 3;            // cg-major tile order
    int row = g * 128 + cg * 16 + cl;          // gate-major output row
    int k = ch * 32 + q * 8 + j;
    float v = 0.f;
    if (k < 128) v = W_hh[row * 128 + k];
    else if (k < 144) v = W_ih[row * 16 + (k - 128)];
    Wg[n] = (_Float16)v;
    return;
  }
  n -= 81920;
  if (n < 98304) {
    int m = n >> 14, r = n & 16383;
    int ct = r >> 11, ch = (r >> 9) & 3, l = (r >> 3) & 63, j = r & 7;
    int q = l >> 4, cl = l & 15;
    int outcol = ct * 16 + cl, k = ch * 32 + q * 8 + j;
    W1p[n] = (_Float16)mW1[(m * 128 + k) * 128 + outcol];
    return;
  }
  n -= 98304;
  if (n < 98304) {
    int m = n >> 14, r = n & 16383;
    int ct = r >> 11, ch = (r >> 9) & 3, l = (r >> 3) & 63, j = r & 7;
    int q = l >> 4, cl = l & 15;
    int outcol = ct * 16 + cl, k = ch * 32 + q * 8 + j;
    W2p[n] = (_Float16)mW2[(m * 128 + k) * 128 + outcol];
    return;
  }
  n -= 98304;
  if (n < 16384) {
    int ct = n >> 11, ch = (n >> 9) & 3, l = (n >> 3) & 63, j = n & 7;
    int q = l >> 4, cl = l & 15;
    int outcol = ct * 16 + cl, k = ch * 32 + q * 8 + j;
    cW1p[n] = (_Float16)cW1[k * 128 + outcol];
    return;
  }
  n -= 16384;
  if (n < 16384) {
    int ct = n >> 11, ch = (n >> 9) & 3, l = (n >> 3) & 63, j = n & 7;
    int q = l >> 4, cl = l & 15;
    int outcol = ct * 16 + cl, k = ch * 32 + q * 8 + j;
    cW2p[n] = (_Float16)cW2[k * 128 + outcol];
    return;
  }
  n -= 16384;
  if (n < 512) bg[n] = b_ih[n] + b_hh[n];
}

// chunk schedule (32 chunks/step, same weights every step):
//   idx 0..7  : Wg + idx*10240, 20 x 1KB
//   idx 8..31 : j=idx-8, m=j>>2, r=j&3 -> (r<2?W1p:W2p)+m*16384+(r&1)*8192, 16 x 1KB
__device__ __forceinline__ void stage_chunk(int idx, _Float16* dst, int w, int lane,
                                            const _Float16* __restrict__ Wg,
                                            const _Float16* __restrict__ W1p,
                                            const _Float16* __restrict__ W2p) {
  const _Float16* src;
  int nblk;
  if (idx < 8) {
    src = Wg + idx * 10240;
    nblk = 20;
  } else {
    int j = idx - 8, m = j >> 2, r = j & 3;
    src = ((r & 2) ? W2p : W1p) + m * 16384 + (r & 1) * 8192;
    nblk = 16;
  }
  for (int i = w; i < nblk; i += 4) {
    __builtin_amdgcn_global_load_lds(
        (const __attribute__((address_space(1))) void*)(src + i * 512 + lane * 8),
        (__attribute__((address_space(3))) void*)(dst + i * 512 + lane * 8),
        16, 0, 0);
  }
}

__device__ __forceinline__ f32x4 mfma16(f16x8 a, f16x8 b, f32x4 c) {
  return __builtin_amdgcn_mfma_f32_16x16x32_f16(a, b, c, 0, 0, 0);
}

// one half (4 col-tiles) of a 128x128 GEMM from a staged LDS buffer
__device__ __forceinline__ void gemm_half(const f16x8 (&a)[2][4], const _Float16* buf,
                                          int lane, f32x4 (&acc)[8][2], int base) {
#pragma unroll
  for (int ctl = 0; ctl < 4; ++ctl) {
    const _Float16* bp = buf + ctl * 2048 + lane * 8;
    f32x4 a0 = {0.f, 0.f, 0.f, 0.f};
    f32x4 a1 = {0.f, 0.f, 0.f, 0.f};
#pragma unroll
    for (int ch = 0; ch < 4; ++ch) {
      f16x8 b = *(const f16x8*)(bp + ch * 512);
      a0 = mfma16(a[0][ch], b, a0);
      a1 = mfma16(a[1][ch], b, a1);
    }
    acc[base + ctl][0] = a0;
    acc[base + ctl][1] = a1;
  }
}

// ---- main decoder: 256 blocks x 4 waves; wave owns 32 rows end-to-end ----
__global__ __launch_bounds__(256, 1) void mmdec_main(
    const float* __restrict__ last_obs_rel, const float* __restrict__ h0, const float* __restrict__ c0,
    const float* __restrict__ W_se, const float* __restrict__ b_se,
    const float* __restrict__ mg1w, const float* __restrict__ mg1b,
    const float* __restrict__ mg2w, const float* __restrict__ mg2b,
    const float* __restrict__ mWo, const float* __restrict__ mbo,
    const float* __restrict__ cg1w, const float* __restrict__ cg1b,
    const float* __restrict__ cg2w, const float* __restrict__ cg2b,
    const float* __restrict__ cWo, const float* __restrict__ cbo,
    const _Float16* __restrict__ Wg, const _Float16* __restrict__ W1p, const _Float16* __restrict__ W2p,
    const _Float16* __restrict__ cW1p, const _Float16* __restrict__ cW2p, const float* __restrict__ bgp,
    float* __restrict__ out) {
  // LDS map (bytes): stage 2x20480 | h 128x336 | t1 128x272 | rel 128x12 f32
  __shared__ __align__(16) unsigned char smem[124928];
  _Float16* stage0 = (_Float16*)smem;                       // [0, 40960)
  unsigned char* h_base = smem + 40960;                     // [40960, 83968)
  unsigned char* t1_base = smem + 83968;                    // [83968, 118784)
  float* rel_all = (float*)(smem + 118784);                 // [118784, 124928)

  const int tid = threadIdx.x;
  const int w = tid >> 6;       // wave id: owns rows [32w, 32w+32) of block
  const int lane = tid & 63;
  const int q = lane >> 4, cl = lane & 15;
  const int rowbase = blockIdx.x * 128 + w * 32;            // wave's first global row

  auto hrow = [&](int r) -> _Float16* { return (_Float16*)(h_base + (w * 32 + r) * 336); };
  auto t1row = [&](int r) -> _Float16* { return (_Float16*)(t1_base + (w * 32 + r) * 272); };
  float* relw = rel_all + w * 32 * 12;

  auto sbuf = [&](int idx) -> _Float16* { return stage0 + ((idx & 1) ? 10240 : 0); };

  // ---- init: h0 -> LDS f16 (half row per lane) ----
  {
    const int rr = lane >> 1, half = lane & 1;
    const float* src = h0 + (size_t)(rowbase + rr) * HD + half * 64;
    _Float16* dst = hrow(rr) + half * 64;
#pragma unroll
    for (int i = 0; i < 64; i += 8) {
      f16x8 v;
#pragma unroll
      for (int k = 0; k < 8; ++k) v[k] = (_Float16)src[i + k];
      *(f16x8*)(dst + i) = v;
    }
    // x = selu(tile(last_obs_rel,6) @ W_se.T + b_se)
    const float r0 = last_obs_rel[(size_t)(rowbase + rr) * 2 + 0];
    const float r1 = last_obs_rel[(size_t)(rowbase + rr) * 2 + 1];
    const int e0 = half * 8;
    f16x8 v;
#pragma unroll
    for (int i = 0; i < 8; ++i) {
      const int e = e0 + i;
      float acc = b_se[e];
#pragma unroll
      for (int j = 0; j < 12; ++j) acc += ((j & 1) ? r1 : r0) * W_se[e * 12 + j];
      v[i] = (_Float16)selu_(acc);
    }
    *(f16x8*)(hrow(rr) + 128 + e0) = v;
    if (lane < 32) {  // zero pad cols 144..159
      f16x8 z;
#pragma unroll
      for (int i = 0; i < 8; ++i) z[i] = (_Float16)0.f;
      *(f16x8*)(hrow(lane) + 144) = z;
      *(f16x8*)(hrow(lane) + 152) = z;
    }
  }
  // ---- init: c0 in C-layout regs [rt][cg] ----
  f32x4 cacc[2][8];
#pragma unroll
  for (int rt = 0; rt < 2; ++rt)
#pragma unroll
    for (int cg = 0; cg < 8; ++cg)
#pragma unroll
      for (int r = 0; r < 4; ++r)
        cacc[rt][cg][r] = c0[(size_t)(rowbase + rt * 16 + q * 4 + r) * HD + cg * 16 + cl];
  float bgh[8][4];
#pragma unroll
  for (int cg = 0; cg < 8; ++cg)
#pragma unroll
    for (int g = 0; g < 4; ++g) bgh[cg][g] = bgp[g * 128 + cg * 16 + cl];

  // prime the pipeline: stage chunk 0
  stage_chunk(0, sbuf(0), w, lane, Wg, W1p, W2p);
  __syncthreads();

  const size_t confbase = (size_t)B_ROWS * MM * TT * 2;

  for (int t = 0; t < TT; ++t) {
    // ======== LSTM: [h|x|0](K=160) @ Wg^T; c update; h(t) scatter ========
    f16x8 afr[2][5];
#pragma unroll
    for (int rt = 0; rt < 2; ++rt)
#pragma unroll
      for (int ch = 0; ch < 5; ++ch)
        afr[rt][ch] = *(const f16x8*)(hrow(rt * 16 + cl) + ch * 32 + q * 8);

    for (int cg = 0; cg < 8; ++cg) {  // chunk idx = cg; contains gates i,f,g,o for cg
      stage_chunk((cg + 1) & 31, sbuf(cg + 1), w, lane, Wg, W1p, W2p);
      const _Float16* buf = sbuf(cg);
      f32x4 gacc[4][2];
#pragma unroll
      for (int g = 0; g < 4; ++g)
#pragma unroll
        for (int rt = 0; rt < 2; ++rt) gacc[g][rt] = f32x4{0.f, 0.f, 0.f, 0.f};
#pragma unroll
      for (int g = 0; g < 4; ++g) {
        const _Float16* bp = buf + g * 2560 + lane * 8;
#pragma unroll
        for (int ch = 0; ch < 5; ++ch) {
          f16x8 b = *(const f16x8*)(bp + ch * 512);
          gacc[g][0] = mfma16(afr[0][ch], b, gacc[g][0]);
          gacc[g][1] = mfma16(afr[1][ch], b, gacc[g][1]);
        }
      }
#pragma unroll
      for (int rt = 0; rt < 2; ++rt)
#pragma unroll
        for (int r = 0; r < 4; ++r) {
          const float iv = sigm(gacc[0][rt][r] + bgh[cg][0]);
          const float fv = sigm(gacc[1][rt][r] + bgh[cg][1]);
          const float gv = tanhf_(gacc[2][rt][r] + bgh[cg][2]);
          const float ov = sigm(gacc[3][rt][r] + bgh[cg][3]);
          const float cn = fv * cacc[rt][cg][r] + iv * gv;
          cacc[rt][cg][r] = cn;
          hrow(rt * 16 + q * 4 + r)[cg * 16 + cl] = (_Float16)(ov * tanhf_(cn));
        }
      __syncthreads();
    }

    // ======== 6 mode heads (wave-local state; barriers only for staging) ========
    for (int m = 0; m < MM; ++m) {
      const int base = 8 + m * 4;
      f16x8 frag[2][4];
#pragma unroll
      for (int rt = 0; rt < 2; ++rt)
#pragma unroll
        for (int ch = 0; ch < 4; ++ch)
          frag[rt][ch] = *(const f16x8*)(hrow(rt * 16 + cl) + ch * 32 + q * 8);

      f32x4 acc1[8][2];
      stage_chunk((base + 1) & 31, sbuf(base + 1), w, lane, Wg, W1p, W2p);
      gemm_half(frag, sbuf(base), lane, acc1, 0);
      __syncthreads();
      stage_chunk((base + 2) & 31, sbuf(base + 2), w, lane, Wg, W1p, W2p);
      gemm_half(frag, sbuf(base + 1), lane, acc1, 4);
      // GN1 + t1 write overlap the staged load
      f32x4 mean[2], rstd[2];
#pragma unroll
      for (int rt = 0; rt < 2; ++rt) {
        f32x4 s1 = {0.f, 0.f, 0.f, 0.f}, s2 = {0.f, 0.f, 0.f, 0.f};
#pragma unroll
        for (int ct = 0; ct < 8; ++ct) { s1 += acc1[ct][rt]; s2 += acc1[ct][rt] * acc1[ct][rt]; }
#pragma unroll
        for (int sh = 1; sh < 16; sh <<= 1) { s1 += shx4(s1, sh); s2 += shx4(s2, sh); }
        mean[rt] = s1 * (1.f / 128.f);
#pragma unroll
        for (int r = 0; r < 4; ++r)
          rstd[rt][r] = rsqrtf(s2[r] * (1.f / 128.f) - mean[rt][r] * mean[rt][r] + 1e-5f);
      }
#pragma unroll
      for (int ct = 0; ct < 8; ++ct) {
        const float g1 = mg1w[m * HD + ct * 16 + cl];
        const float b1 = mg1b[m * HD + ct * 16 + cl];
#pragma unroll
        for (int rt = 0; rt < 2; ++rt)
#pragma unroll
          for (int r = 0; r < 4; ++r) {
            float v = (acc1[ct][rt][r] - mean[rt][r]) * rstd[rt][r] * g1 + b1;
            t1row(rt * 16 + q * 4 + r)[ct * 16 + cl] = (_Float16)fmaxf(v, 0.f);
          }
      }
      __syncthreads();
      // gemm2 from t1 (same-wave LDS write->read is in-order; no barrier needed)
      f16x8 at1[2][4];
#pragma unroll
      for (int rt = 0; rt < 2; ++rt)
#pragma unroll
        for (int ch = 0; ch < 4; ++ch)
          at1[rt][ch] = *(const f16x8*)(t1row(rt * 16 + cl) + ch * 32 + q * 8);
      f32x4 acc2[8][2];
      stage_chunk((base + 3) & 31, sbuf(base + 3), w, lane, Wg, W1p, W2p);
      gemm_half(at1, sbuf(base + 2), lane, acc2, 0);
      __syncthreads();
      stage_chunk((base + 4) & 31, sbuf(base + 4), w, lane, Wg, W1p, W2p);
      gemm_half(at1, sbuf(base + 3), lane, acc2, 4);
      // GN2 + residual + out-proj
#pragma unroll
      for (int rt = 0; rt < 2; ++rt) {
        f32x4 s1 = {0.f, 0.f, 0.f, 0.f}, s2 = {0.f, 0.f, 0.f, 0.f};
#pragma unroll
        for (int ct = 0; ct < 8; ++ct) { s1 += acc2[ct][rt]; s2 += acc2[ct][rt] * acc2[ct][rt]; }
#pragma unroll
        for (int sh = 1; sh < 16; sh <<= 1) { s1 += shx4(s1, sh); s2 += shx4(s2, sh); }
        mean[rt] = s1 * (1.f / 128.f);
#pragma unroll
        for (int r = 0; r < 4; ++r)
          rstd[rt][r] = rsqrtf(s2[r] * (1.f / 128.f) - mean[rt][r] * mean[rt][r] + 1e-5f);
      }
      f32x4 po0[2], po1[2];
#pragma unroll
      for (int rt = 0; rt < 2; ++rt) { po0[rt] = f32x4{0.f, 0.f, 0.f, 0.f}; po1[rt] = f32x4{0.f, 0.f, 0.f, 0.f}; }
#pragma unroll
      for (int ct = 0; ct < 8; ++ct) {
        const float g2 = mg2w[m * HD + ct * 16 + cl];
        const float b2 = mg2b[m * HD + ct * 16 + cl];
        const float w0 = mWo[((size_t)m * HD + ct * 16 + cl) * 2 + 0];
        const float w1 = mWo[((size_t)m * HD + ct * 16 + cl) * 2 + 1];
#pragma unroll
        for (int rt = 0; rt < 2; ++rt)
#pragma unroll
          for (int r = 0; r < 4; ++r) {
            const float hres = (float)hrow(rt * 16 + q * 4 + r)[ct * 16 + cl];
            float v = (acc2[ct][rt][r] - mean[rt][r]) * rstd[rt][r] * g2 + b2 + hres;
            v = fmaxf(v, 0.f);
            po0[rt][r] += v * w0;
            po1[rt][r] += v * w1;
          }
      }
#pragma unroll
      for (int sh = 1; sh < 16; sh <<= 1)
#pragma unroll
        for (int rt = 0; rt < 2; ++rt) { po0[rt] += shx4(po0[rt], sh); po1[rt] += shx4(po1[rt], sh); }
      if (cl < 2) {
#pragma unroll
        for (int rt = 0; rt < 2; ++rt)
#pragma unroll
          for (int r = 0; r < 4; ++r) {
            const int rl_ = rt * 16 + q * 4 + r;
            const float val = (cl ? po1[rt][r] : po0[rt][r]) + mbo[m * 2 + cl];
            out[(((size_t)(rowbase + rl_) * MM + m) * TT + t) * 2 + cl] = val;
            relw[rl_ * 12 + m * 2 + cl] = val;
          }
      }
      __syncthreads();
    }

    // ======== xin = selu(rel @ W_se.T + b_se) -> x cols (wave-local) ========
    {
      const int rr = lane >> 1, e0 = (lane & 1) * 8;
      float rl[12];
#pragma unroll
      for (int j = 0; j < 12; ++j) rl[j] = relw[rr * 12 + j];
      f16x8 v;
#pragma unroll
      for (int i = 0; i < 8; ++i) {
        const int e = e0 + i;
        float acc = b_se[e];
#pragma unroll
        for (int j = 0; j < 12; ++j) acc += rl[j] * W_se[e * 12 + j];
        v[i] = (_Float16)selu_(acc);
      }
      *(f16x8*)(hrow(rr) + 128 + e0) = v;
    }
    // no barrier: h/x/rel are wave-private; staging WAR is covered by the
    // mode-5 sync above (next overwrite of that buffer is 2 chunks away)
  }

  // ======== confidence head on hT (wave-local; weights from global) ========
  {
    f16x8 frag[2][4];
#pragma unroll
    for (int rt = 0; rt < 2; ++rt)
#pragma unroll
      for (int ch = 0; ch < 4; ++ch)
        frag[rt][ch] = *(const f16x8*)(hrow(rt * 16 + cl) + ch * 32 + q * 8);
    f32x4 acc1[8][2];
#pragma unroll
    for (int ct = 0; ct < 8; ++ct) {
      const _Float16* bp = cW1p + ct * 2048 + lane * 8;
      f32x4 a0 = {0.f, 0.f, 0.f, 0.f}, a1 = {0.f, 0.f, 0.f, 0.f};
#pragma unroll
      for (int ch = 0; ch < 4; ++ch) {
        f16x8 b = *(const f16x8*)(bp + ch * 512);
        a0 = mfma16(frag[0][ch], b, a0);
        a1 = mfma16(frag[1][ch], b, a1);
      }
      acc1[ct][0] = a0;
      acc1[ct][1] = a1;
    }
    f32x4 mean[2], rstd[2];
#pragma unroll
    for (int rt = 0; rt < 2; ++rt) {
      f32x4 s1 = {0.f, 0.f, 0.f, 0.f}, s2 = {0.f, 0.f, 0.f, 0.f};
#pragma unroll
      for (int ct = 0; ct < 8; ++ct) { s1 += acc1[ct][rt]; s2 += acc1[ct][rt] * acc1[ct][rt]; }
#pragma unroll
      for (int sh = 1; sh < 16; sh <<= 1) { s1 += shx4(s1, sh); s2 += shx4(s2, sh); }
      mean[rt] = s1 * (1.f / 128.f);
#pragma unroll
      for (int r = 0; r < 4; ++r)
        rstd[rt][r] = rsqrtf(s2[r] * (1.f / 128.f) - mean[rt][r] * mean[rt][r] + 1e-5f);
    }
#pragma unroll
    for (int ct = 0; ct < 8; ++ct) {
      const float g1 = cg1w[ct * 16 + cl];
      const float b1 = cg1b[ct * 16 + cl];
#pragma unroll
      for (int rt = 0; rt < 2; ++rt)
#pragma unroll
        for (int r = 0; r < 4; ++r) {
          float v = (acc1[ct][rt][r] - mean[rt][r]) * rstd[rt][r] * g1 + b1;
          t1row(rt * 16 + q * 4 + r)[ct * 16 + cl] = (_Float16)fmaxf(v, 0.f);
        }
    }
    f16x8 at1[2][4];
#pragma unroll
    for (int rt = 0; rt < 2; ++rt)
#pragma unroll
      for (int ch = 0; ch < 4; ++ch)
        at1[rt][ch] = *(const f16x8*)(t1row(rt * 16 + cl) + ch * 32 + q * 8);
    f32x4 acc2[8][2];
#pragma unroll
    for (int ct = 0; ct < 8; ++ct) {
      const _Float16* bp = cW2p + ct * 2048 + lane * 8;
      f32x4 a0 = {0.f, 0.f, 0.f, 0.f}, a1 = {0.f, 0.f, 0.f, 0.f};
#pragma unroll
      for (int ch = 0; ch < 4; ++ch) {
        f16x8 b = *(const f16x8*)(bp + ch * 512);
        a0 = mfma16(at1[0][ch], b, a0);
        a1 = mfma16(at1[1][ch], b, a1);
      }
      acc2[ct][0] = a0;
      acc2[ct][1] = a1;
    }
#pragma unroll
    for (int rt = 0; rt < 2; ++rt) {
      f32x4 s1 = {0.f, 0.f, 0.f, 0.f}, s2 = {0.f, 0.f, 0.f, 0.f};
#pragma unroll
      for (int ct = 0; ct < 8; ++ct) { s1 += acc2[ct][rt]; s2 += acc2[ct][rt] * acc2[ct][rt]; }
#pragma unroll
      for (int sh = 1; sh < 16; sh <<= 1) { s1 += shx4(s1, sh); s2 += shx4(s2, sh); }
      mean[rt] = s1 * (1.f / 128.f);
#pragma unroll
      for (int r = 0; r < 4; ++r)
        rstd[rt][r] = rsqrtf(s2[r] * (1.f / 128.f) - mean[rt][r] * mean[rt][r] + 1e-5f);
    }
    float pl[2][4][6];
#pragma unroll
    for (int rt = 0; rt < 2; ++rt)
#pragma unroll
      for (int r = 0; r < 4; ++r)
#pragma unroll
        for (int k = 0; k < 6; ++k) pl[rt][r][k] = 0.f;
#pragma unroll
    for (int ct = 0; ct < 8; ++ct) {
      const float g2 = cg2w[ct * 16 + cl];
      const float b2 = cg2b[ct * 16 + cl];
      float wo[6];
#pragma unroll
      for (int k = 0; k < 6; ++k) wo[k] = cWo[(ct * 16 + cl) * 6 + k];
#pragma unroll
      for (int rt = 0; rt < 2; ++rt)
#pragma unroll
        for (int r = 0; r < 4; ++r) {
          const float hres = (float)hrow(rt * 16 + q * 4 + r)[ct * 16 + cl];
          float v = (acc2[ct][rt][r] - mean[rt][r]) * rstd[rt][r] * g2 + b2 + hres;
          v = fmaxf(v, 0.f);
#pragma unroll
          for (int k = 0; k < 6; ++k) pl[rt][r][k] += v * wo[k];
        }
    }
#pragma unroll
    for (int sh = 1; sh < 16; sh <<= 1)
#pragma unroll
      for (int rt = 0; rt < 2; ++rt)
#pragma unroll
        for (int r = 0; r < 4; ++r)
#pragma unroll
          for (int k = 0; k < 6; ++k) pl[rt][r][k] += __shfl_xor(pl[rt][r][k], sh, 64);
    if (cl == 0) {
#pragma unroll
      for (int rt = 0; rt < 2; ++rt)
#pragma unroll
        for (int r = 0; r < 4; ++r) {
          float l[6];
#pragma unroll
          for (int k = 0; k < 6; ++k) l[k] = pl[rt][r][k] + cbo[k];
          float mx = l[0];
#pragma unroll
          for (int k = 1; k < 6; ++k) mx = fmaxf(mx, l[k]);
          float s = 0.f;
#pragma unroll
          for (int k = 0; k < 6; ++k) { l[k] = __expf(l[k] - mx); s += l[k]; }
          const float inv = fast_rcp(s);
#pragma unroll
          for (int k = 0; k < 6; ++k)
            out[confbase + (size_t)(rowbase + rt * 16 + q * 4 + r) * 6 + k] = l[k] * inv;
        }
    }
  }
}

extern "C" void kernel_launch(void* const* d_in, const int* in_sizes, int n_in,
                              void* d_out, int out_size, void* d_ws, size_t ws_size,
                              hipStream_t stream) {
  (void)in_sizes; (void)n_in; (void)out_size; (void)ws_size;
  const float* last_obs_rel = (const float*)d_in[1];
  const float* h0   = (const float*)d_in[2];
  const float* c0   = (const float*)d_in[3];
  const float* W_se = (const float*)d_in[4];
  const float* b_se = (const float*)d_in[5];
  const float* W_ih = (const float*)d_in[6];
  const float* W_hh = (const float*)d_in[7];
  const float* b_ih = (const float*)d_in[8];
  const float* b_hh = (const float*)d_in[9];
  const float* mW1  = (const float*)d_in[10];
  const float* mg1w = (const float*)d_in[11];
  const float* mg1b = (const float*)d_in[12];
  const float* mW2  = (const float*)d_in[13];
  const float* mg2w = (const float*)d_in[14];
  const float* mg2b = (const float*)d_in[15];
  const float* mWo  = (const float*)d_in[16];
  const float* mbo  = (const float*)d_in[17];
  const float* cW1  = (const float*)d_in[18];
  const float* cg1w = (const float*)d_in[19];
  const float* cg1b = (const float*)d_in[20];
  const float* cW2  = (const float*)d_in[21];
  const float* cg2w = (const float*)d_in[22];
  const float* cg2b = (const float*)d_in[23];
  const float* cWo  = (const float*)d_in[24];
  const float* cbo  = (const float*)d_in[25];

  char* ws = (char*)d_ws;
  _Float16* Wg   = (_Float16*)(ws + 0);       // 512*160 f16   = 163840 B
  _Float16* W1p  = (_Float16*)(ws + 163840);  // 6*128*128 f16 = 196608 B
  _Float16* W2p  = (_Float16*)(ws + 360448);  // 6*128*128 f16 = 196608 B
  _Float16* cW1p = (_Float16*)(ws + 557056);  // 128*128 f16   =  32768 B
  _Float16* cW2p = (_Float16*)(ws + 589824);  // 128*128 f16   =  32768 B
  float*    bg   = (float*)   (ws + 622592);  // 512 f32       =   2048 B

  prep_weights<<<1218, 256, 0, stream>>>(W_ih, W_hh, b_ih, b_hh, mW1, mW2, cW1, cW2,
                                         Wg, W1p, W2p, cW1p, cW2p, bg);
  mmdec_main<<<B_ROWS / 128, 256, 0, stream>>>(last_obs_rel, h0, c0, W_se, b_se,
                                               mg1w, mg1b, mg2w, mg2b, mWo, mbo,
                                               cg1w, cg1b, cg2w, cg2b, cWo, cbo,
                                               Wg, W1p, W2p, cW1p, cW2p, bg, (float*)d_out);
}